// Round 7
// baseline (765.404 us; speedup 1.0000x reference)
//
#include <hip/hip_runtime.h>
#include <hip/hip_bf16.h>
#include <math.h>

// Problem constants (fixed by the reference)
#define NB    4096      // number of anchors  (B / GROUP)
#define BB    20480     // total rows of inputs = columns of sim
#define DD    512       // feature dim
#define EPc    0.1f
#define BETAc  10.0f
#define ALPHAc 2.0f
#define LMDAc  1.0f
// LSE shift: masked args BETA*(s-1) span ~[-700, 1400].
#define SHIFT  1400.0

typedef __attribute__((ext_vector_type(8))) short bf16x8;   // 8 bf16 (4 VGPRs)
typedef __attribute__((ext_vector_type(4))) float f32x4;    // MFMA accumulator
typedef unsigned int u32;

// global_load_lds, 16B per lane. LDS dest is wave-uniform base + lane*16 (m104);
// global src is per-lane (pre-swizzled there, rule 21).
#define GLOAD16(gp, lp) \
    __builtin_amdgcn_global_load_lds((const __attribute__((address_space(1))) u32*)(gp), \
                                     (__attribute__((address_space(3))) u32*)(lp), 16, 0, 0)

// ---- monotone float <-> uint key (for atomicMax on float incl. negatives) ----
__device__ __forceinline__ unsigned fenc(float x) {
    unsigned b = __float_as_uint(x);
    return (b & 0x80000000u) ? ~b : (b | 0x80000000u);
}
__device__ __forceinline__ float fdec(unsigned k) {
    unsigned b = (k & 0x80000000u) ? (k ^ 0x80000000u) : ~k;
    return __uint_as_float(b);
}

// ---- f32 pair -> packed bf16 hi / lo words ----
__device__ __forceinline__ void split2(float a, float b, u32* h, u32* l) {
    __hip_bfloat16 ha = __float2bfloat16(a);
    __hip_bfloat16 hb = __float2bfloat16(b);
    unsigned short ba, bb;
    __builtin_memcpy(&ba, &ha, 2); __builtin_memcpy(&bb, &hb, 2);
    float fa = __uint_as_float((u32)ba << 16);
    float fb = __uint_as_float((u32)bb << 16);
    __hip_bfloat16 la = __float2bfloat16(a - fa);
    __hip_bfloat16 lb = __float2bfloat16(b - fb);
    unsigned short ca, cb;
    __builtin_memcpy(&ca, &la, 2); __builtin_memcpy(&cb, &lb, 2);
    *h = (u32)ba | ((u32)bb << 16);
    *l = (u32)ca | ((u32)cb << 16);
}

// ============================================================================
// Kernel 0: split inputs into Hi/Lo bf16 arrays (row-major [BB][DD], packed).
// ============================================================================
__global__ __launch_bounds__(256) void split_kernel(const float* __restrict__ inp,
        u32* __restrict__ hi, u32* __restrict__ lo)
{
    const size_t e = ((size_t)blockIdx.x * 256 + threadIdx.x) * 8;
    float4 x0 = *(const float4*)(inp + e);
    float4 x1 = *(const float4*)(inp + e + 4);
    u32 h[4], l[4];
    split2(x0.x, x0.y, &h[0], &l[0]);
    split2(x0.z, x0.w, &h[1], &l[1]);
    split2(x1.x, x1.y, &h[2], &l[2]);
    split2(x1.z, x1.w, &h[3], &l[3]);
    *(uint4*)(hi + e / 2) = make_uint4(h[0], h[1], h[2], h[3]);
    *(uint4*)(lo + e / 2) = make_uint4(l[0], l[1], l[2], l[3]);
}

// ============================================================================
// Kernel 1: pos[i][g-1] = f_i . inputs[5i+g] (exact f32); posmin[i] = min
// ============================================================================
__global__ __launch_bounds__(256) void pos_kernel(const float* __restrict__ inp,
        float* __restrict__ pos, float* __restrict__ posmin)
{
    const int wid  = threadIdx.x >> 6;
    const int lane = threadIdx.x & 63;
    const int i = blockIdx.x * 4 + wid;
    const float* f = inp + (size_t)(5 * i) * DD + lane * 8;
    float4 fa = *(const float4*)(f);
    float4 fb = *(const float4*)(f + 4);
    float pmin = INFINITY;
    #pragma unroll
    for (int g = 1; g < 5; ++g) {
        const float* x = inp + (size_t)(5 * i + g) * DD + lane * 8;
        float4 xa = *(const float4*)(x);
        float4 xb = *(const float4*)(x + 4);
        float s = fa.x*xa.x + fa.y*xa.y + fa.z*xa.z + fa.w*xa.w
                + fb.x*xb.x + fb.y*xb.y + fb.z*xb.z + fb.w*xb.w;
        #pragma unroll
        for (int m = 1; m < 64; m <<= 1) s += __shfl_xor(s, m, 64);
        if (lane == 0) pos[i * 4 + (g - 1)] = s;
        pmin = fminf(pmin, s);
    }
    if (lane == 0) posmin[i] = pmin;
}

// ============================================================================
// Per-row LSE/max/count fold + atomics for one accumulator row-register.
// ============================================================================
__device__ __forceinline__ void row_epilogue(int i, int c0, int wc, int l15,
        float s0, float s1, float s2, float s3,
        const float* __restrict__ posmin, unsigned* __restrict__ negkey,
        double* __restrict__ msum, unsigned* __restrict__ cntn)
{
    const float th = posmin[i] - EPc;     // strict >
    float vmax = -INFINITY;
    float lM   = -INFINITY;
    float lS   = 0.f;
    int   vcnt = 0;
    float sv[4] = {s0, s1, s2, s3};
    float args[4]; bool msk[4];
    #pragma unroll
    for (int fc = 0; fc < 4; ++fc) {
        const int c = c0 + wc + fc * 16 + l15;
        const float s = sv[fc];
        const bool nonown = ((c / 5) != i);
        msk[fc]  = nonown && (s > th);
        args[fc] = BETAc * (s - LMDAc);
        if (nonown)  vmax = fmaxf(vmax, s);
        if (msk[fc]) { vcnt += 1; lM = fmaxf(lM, args[fc]); }
    }
    #pragma unroll
    for (int fc = 0; fc < 4; ++fc)
        if (msk[fc]) lS += __expf(args[fc] - lM);
    #pragma unroll
    for (int m = 1; m < 16; m <<= 1) {
        vmax  = fmaxf(vmax, __shfl_xor(vmax, m, 64));
        vcnt += __shfl_xor(vcnt, m, 64);
        float oM = __shfl_xor(lM, m, 64);
        float oS = __shfl_xor(lS, m, 64);
        if (oS != 0.f) {
            if (lS == 0.f)      { lM = oM; lS = oS; }
            else if (lM >= oM)  { lS += oS * __expf(oM - lM); }
            else                { lS = oS + lS * __expf(lM - oM); lM = oM; }
        }
    }
    if (l15 == 0) {
        atomicMax(&negkey[i], fenc(vmax));
        atomicAdd(&cntn[i], (unsigned)vcnt);
        if (lS > 0.f) {
            double e = (double)lM - SHIFT;
            if (e > 690.0) e = 690.0;
            double Dv = exp(e) * (double)lS;
            if (!(Dv < 1e300)) Dv = 1e300;    // also catches nan
            atomicAdd(&msum[i], Dv);
        }
    }
}

// ============================================================================
// Kernel 2 (fast path): MFMA sim GEMM, pre-split bf16 via global_load_lds.
// BM=256 x BN=128 tile, BK=32, 4 waves in 2x2 grid, wave tile 128x64
// (8x4 frags of 16x16x32) -> 65 FLOP per LDS byte (was 49 at 64x64).
// LDS 48 KB single-buffered, linear rows of 64B; chunk swizzle c^((row>>1)&3)
// on the GLOBAL SOURCE (write side, rule 21) and on the ds_read (read side).
// ============================================================================
__global__ __launch_bounds__(256) void sim_mfma3(const u32* __restrict__ hi,
        const u32* __restrict__ lo, const float* __restrict__ posmin,
        unsigned* __restrict__ negkey, double* __restrict__ msum,
        unsigned* __restrict__ cntn)
{
    __shared__ u32 AsHi[256 * 16];   // 256 rows x 64B = 16 KB
    __shared__ u32 AsLo[256 * 16];
    __shared__ u32 BsHi[128 * 16];   // 128 rows x 64B = 8 KB
    __shared__ u32 BsLo[128 * 16];

    const int t    = threadIdx.x;
    const int bj   = blockIdx.x % (BB / 128);   // 160 col tiles
    const int bi   = blockIdx.x / (BB / 128);   // 16 row tiles
    const int i0   = bi * 256;
    const int c0   = bj * 128;
    const int lane = t & 63;
    const int w    = t >> 6;
    const int wr   = (w >> 1) * 128;            // wave row offset (0 or 128)
    const int wc   = (w & 1) * 64;              // wave col offset (0 or 64)
    const int l15  = lane & 15;
    const int l4   = lane >> 4;

    // ---- staging: wave w covers A rows [w*64, w*64+64), B rows [w*32, w*32+32)
    const int srA = w * 64 + (lane >> 2);       // j in 0..3 adds 16 rows
    const int srB = w * 32 + (lane >> 2);       // j in 0..1 adds 16 rows
    const int scp = lane & 3;                   // stored chunk slot
    const int scA = scp ^ ((srA >> 1) & 3);     // logical chunk fetched
    const int scB = scp ^ ((srB >> 1) & 3);     // (+16 rows keeps swizzle, 8&3==0)
    const size_t offA = (size_t)(5 * (i0 + srA)) * (DD * 2) + scA * 16;
    const size_t offB = (size_t)(c0 + srB)      * (DD * 2) + scB * 16;
    const char* pAh = (const char*)hi + offA;
    const char* pAl = (const char*)lo + offA;
    const char* pBh = (const char*)hi + offB;
    const char* pBl = (const char*)lo + offB;
    u32* const ldsA  = AsHi + (w * 64) * 16;    // wave-uniform dests
    u32* const ldsAl = AsLo + (w * 64) * 16;
    u32* const ldsB  = BsHi + (w * 32) * 16;
    u32* const ldsBl = BsLo + (w * 32) * 16;

    f32x4 acc[8][4];
    #pragma unroll
    for (int a = 0; a < 8; ++a)
        #pragma unroll
        for (int b = 0; b < 4; ++b) acc[a][b] = (f32x4)0.f;

    // swizzled LDS byte offsets for fragment reads
    int aoff[8], boff[4];
    #pragma unroll
    for (int f = 0; f < 8; ++f) {
        const int row = wr + f * 16 + l15;
        aoff[f] = row * 64 + ((l4 ^ ((row >> 1) & 3)) * 16);
    }
    #pragma unroll
    for (int f = 0; f < 4; ++f) {
        const int col = wc + f * 16 + l15;
        boff[f] = col * 64 + ((l4 ^ ((col >> 1) & 3)) * 16);
    }

    for (int kb = 0; kb < DD / 32; ++kb) {
        __syncthreads();                       // prev iter's readers done
        #pragma unroll
        for (int j = 0; j < 4; ++j) {
            GLOAD16(pAh + (size_t)j * 81920, ldsA  + j * 256);
            GLOAD16(pAl + (size_t)j * 81920, ldsAl + j * 256);
        }
        #pragma unroll
        for (int j = 0; j < 2; ++j) {
            GLOAD16(pBh + (size_t)j * 16384, ldsB  + j * 256);
            GLOAD16(pBl + (size_t)j * 16384, ldsBl + j * 256);
        }
        pAh += 64; pAl += 64; pBh += 64; pBl += 64;
        asm volatile("s_waitcnt vmcnt(0)" ::: "memory");
        __syncthreads();                       // tile visible to all waves

        bf16x8 bh[4], bl[4];
        #pragma unroll
        for (int fc = 0; fc < 4; ++fc) {
            bh[fc] = *(const bf16x8*)((const char*)BsHi + boff[fc]);
            bl[fc] = *(const bf16x8*)((const char*)BsLo + boff[fc]);
        }
        #pragma unroll
        for (int fr = 0; fr < 8; ++fr) {
            bf16x8 ah = *(const bf16x8*)((const char*)AsHi + aoff[fr]);
            bf16x8 al = *(const bf16x8*)((const char*)AsLo + aoff[fr]);
            #pragma unroll
            for (int fc = 0; fc < 4; ++fc) {
                acc[fr][fc] = __builtin_amdgcn_mfma_f32_16x16x32_bf16(ah, bh[fc], acc[fr][fc], 0, 0, 0);
                acc[fr][fc] = __builtin_amdgcn_mfma_f32_16x16x32_bf16(ah, bl[fc], acc[fr][fc], 0, 0, 0);
                acc[fr][fc] = __builtin_amdgcn_mfma_f32_16x16x32_bf16(al, bh[fc], acc[fr][fc], 0, 0, 0);
            }
        }
    }

    // ---- fused epilogue. C/D layout: col = lane&15, row = (lane>>4)*4 + reg
    #pragma unroll
    for (int fr = 0; fr < 8; ++fr) {
        #pragma unroll
        for (int reg = 0; reg < 4; ++reg) {
            const int i = i0 + wr + fr * 16 + l4 * 4 + reg;
            row_epilogue(i, c0, wc, l15,
                         acc[fr][0][reg], acc[fr][1][reg],
                         acc[fr][2][reg], acc[fr][3][reg],
                         posmin, negkey, msum, cntn);
        }
    }
}

// ============================================================================
// Kernel 2 (fallback, ws too small): in-kernel cvt, known-good from round 4.
// ============================================================================
__device__ __forceinline__ void cvt8(const float* __restrict__ src,
                                     uint4* __restrict__ dhi, uint4* __restrict__ dlo)
{
    float4 x0 = *(const float4*)(src);
    float4 x1 = *(const float4*)(src + 4);
    float xs[8] = {x0.x, x0.y, x0.z, x0.w, x1.x, x1.y, x1.z, x1.w};
    u32 h[4], l[4];
    #pragma unroll
    for (int p = 0; p < 4; ++p) split2(xs[2*p], xs[2*p+1], &h[p], &l[p]);
    *dhi = make_uint4(h[0], h[1], h[2], h[3]);
    *dlo = make_uint4(l[0], l[1], l[2], l[3]);
}

__global__ __launch_bounds__(256) void sim_mfma(const float* __restrict__ inp,
        const float* __restrict__ posmin, unsigned* __restrict__ negkey,
        double* __restrict__ msum, unsigned* __restrict__ cntn)
{
    __shared__ uint4 AsHi[128][4];
    __shared__ uint4 AsLo[128][4];
    __shared__ uint4 BsHi[128][4];
    __shared__ uint4 BsLo[128][4];

    const int t    = threadIdx.x;
    const int bj   = blockIdx.x % (BB / 128);
    const int bi   = blockIdx.x / (BB / 128);
    const int i0   = bi * 128;
    const int c0   = bj * 128;
    const int lane = t & 63;
    const int w    = t >> 6;
    const int wr   = (w >> 1) * 64;
    const int wc   = (w & 1) * 64;
    const int l15  = lane & 15;
    const int l4   = lane >> 4;

    f32x4 acc[4][4];
    #pragma unroll
    for (int a = 0; a < 4; ++a)
        #pragma unroll
        for (int b = 0; b < 4; ++b) acc[a][b] = (f32x4)0.f;

    const int r0  = t >> 2;
    const int ch0 = t & 3;

    for (int kb = 0; kb < DD; kb += 32) {
        __syncthreads();
        #pragma unroll
        for (int half = 0; half < 2; ++half) {
            const int row = r0 + half * 64;
            const int cs  = ch0 ^ ((row >> 2) & 3);
            cvt8(inp + (size_t)(5 * (i0 + row)) * DD + kb + ch0 * 8,
                 &AsHi[row][cs], &AsLo[row][cs]);
            cvt8(inp + (size_t)(c0 + row) * DD + kb + ch0 * 8,
                 &BsHi[row][cs], &BsLo[row][cs]);
        }
        __syncthreads();

        bf16x8 bh[4], bl[4];
        #pragma unroll
        for (int fc = 0; fc < 4; ++fc) {
            const int col = wc + fc * 16 + l15;
            const int cs  = l4 ^ ((col >> 2) & 3);
            bh[fc] = *(const bf16x8*)&BsHi[col][cs];
            bl[fc] = *(const bf16x8*)&BsLo[col][cs];
        }
        #pragma unroll
        for (int fr = 0; fr < 4; ++fr) {
            const int row = wr + fr * 16 + l15;
            const int cs  = l4 ^ ((row >> 2) & 3);
            bf16x8 ah = *(const bf16x8*)&AsHi[row][cs];
            bf16x8 al = *(const bf16x8*)&AsLo[row][cs];
            #pragma unroll
            for (int fc = 0; fc < 4; ++fc) {
                acc[fr][fc] = __builtin_amdgcn_mfma_f32_16x16x32_bf16(ah, bh[fc], acc[fr][fc], 0, 0, 0);
                acc[fr][fc] = __builtin_amdgcn_mfma_f32_16x16x32_bf16(ah, bl[fc], acc[fr][fc], 0, 0, 0);
                acc[fr][fc] = __builtin_amdgcn_mfma_f32_16x16x32_bf16(al, bh[fc], acc[fr][fc], 0, 0, 0);
            }
        }
    }

    #pragma unroll
    for (int fr = 0; fr < 4; ++fr) {
        #pragma unroll
        for (int reg = 0; reg < 4; ++reg) {
            const int i = i0 + wr + fr * 16 + l4 * 4 + reg;
            row_epilogue(i, c0, wc, l15,
                         acc[fr][0][reg], acc[fr][1][reg],
                         acc[fr][2][reg], acc[fr][3][reg],
                         posmin, negkey, msum, cntn);
        }
    }
}

// ============================================================================
// Kernel 3: finalize.
// ============================================================================
__global__ __launch_bounds__(1024) void fin_kernel(const float* __restrict__ pos,
        const unsigned* __restrict__ negkey, const double* __restrict__ msum,
        const unsigned* __restrict__ cntn, float* __restrict__ out)
{
    const int t = threadIdx.x;
    double lossAcc = 0.0;
    int pAcc = 0, nAcc = 0;
    for (int r = t; r < NB; r += 1024) {
        const float negmax = fdec(negkey[r]);
        const float thr = negmax + EPc;       // strict <
        float Mp = -INFINITY; int pc = 0;
        float pa[4]; bool pm[4];
        #pragma unroll
        for (int g = 0; g < 4; ++g) {
            const float p = pos[r * 4 + g];
            pa[g] = -ALPHAc * (p - LMDAc);
            pm[g] = (p < thr);
            if (pm[g]) { pc += 1; Mp = fmaxf(Mp, pa[g]); }
        }
        double lp = 0.0;
        if (pc > 0) {
            float sp = 0.f;
            #pragma unroll
            for (int g = 0; g < 4; ++g)
                if (pm[g]) sp += __expf(pa[g] - Mp);
            double a = (double)Mp + log((double)sp);
            lp = (a > 30.0 ? a : log1p(exp(a))) / (double)ALPHAc;
        }
        double ln = 0.0;
        double Dsum = msum[r];
        if (Dsum > 0.0) {
            double a = SHIFT + log(Dsum);
            ln = (a > 30.0 ? a : log1p(exp(a))) / (double)BETAc;
        }
        double contrib = lp + ln;
        if (!(contrib < 1e30)) contrib = 1e30;
        lossAcc += contrib;
        pAcc += pc;
        nAcc += (int)cntn[r];
    }
    __shared__ double sl[1024];
    __shared__ int    sp_[1024];
    __shared__ int    sn_[1024];
    sl[t] = lossAcc; sp_[t] = pAcc; sn_[t] = nAcc;
    __syncthreads();
    for (int s = 512; s > 0; s >>= 1) {
        if (t < s) { sl[t] += sl[t + s]; sp_[t] += sp_[t + s]; sn_[t] += sn_[t + s]; }
        __syncthreads();
    }
    if (t == 0) {
        double loss = sl[0] / 4096.0;
        if (!(loss < 1e30)) loss = 1e30;
        out[0] = (float)loss;
        out[1] = (float)sp_[0] / 16384.0f;
        out[2] = (float)sn_[0] / 83865600.0f;
    }
}

// ============================================================================
extern "C" void kernel_launch(void* const* d_in, const int* in_sizes, int n_in,
                              void* d_out, int out_size, void* d_ws, size_t ws_size,
                              hipStream_t stream)
{
    (void)in_sizes; (void)n_in; (void)out_size;
    const float* inp = (const float*)d_in[0];   // (20480, 512) f32; targets unused
    char* ws = (char*)d_ws;
    // ws layout (bytes):
    //   [0      , 65536 )  pos      : 4096*4 f32
    //   [65536  , 81920 )  posmin   : 4096 f32
    //   [81920  , 98304 )  negkey   : 4096 u32
    //   [98304  , 131072)  msum     : 4096 f64
    //   [131072 , 147456)  cntn     : 4096 u32
    //   [147456 , +21.0MB)  Hi bf16 [BB][DD]
    //   [ ...   , +21.0MB)  Lo bf16 [BB][DD]
    float*    pos    = (float*)   (ws);
    float*    posmin = (float*)   (ws + 65536);
    unsigned* negkey = (unsigned*)(ws + 81920);
    double*   msum   = (double*)  (ws + 98304);
    unsigned* cntn   = (unsigned*)(ws + 131072);
    u32*      hi     = (u32*)     (ws + 147456);
    u32*      lo     = (u32*)     (ws + 147456 + (size_t)BB * DD * 2);
    float*    out    = (float*)d_out;
    const size_t need = 147456 + (size_t)BB * DD * 4;   // 42.1 MB

    hipMemsetAsync(ws + 81920, 0, 65536, stream);
    hipLaunchKernelGGL(pos_kernel, dim3(NB / 4), dim3(256), 0, stream, inp, pos, posmin);

    if (ws_size >= need) {
        hipLaunchKernelGGL(split_kernel, dim3(BB * DD / (256 * 8)), dim3(256), 0, stream,
                           inp, hi, lo);
        hipLaunchKernelGGL(sim_mfma3, dim3((NB / 256) * (BB / 128)), dim3(256), 0, stream,
                           hi, lo, posmin, negkey, msum, cntn);
    } else {
        hipLaunchKernelGGL(sim_mfma, dim3((NB / 128) * (BB / 128)), dim3(256), 0, stream,
                           inp, posmin, negkey, msum, cntn);
    }
    hipLaunchKernelGGL(fin_kernel, dim3(1), dim3(1024), 0, stream, pos, negkey, msum, cntn, out);
}

// Round 8
// 525.620 us; speedup vs baseline: 1.4562x; 1.4562x over previous
//
#include <hip/hip_runtime.h>
#include <hip/hip_bf16.h>
#include <math.h>

// Problem constants (fixed by the reference)
#define NB    4096      // number of anchors  (B / GROUP)
#define BB    20480     // total rows of inputs = columns of sim
#define DD    512       // feature dim
#define EPc    0.1f
#define BETAc  10.0f
#define ALPHAc 2.0f
#define LMDAc  1.0f
// LSE shift: masked args BETA*(s-1) span ~[-700, 1400].
#define SHIFT  1400.0

typedef __attribute__((ext_vector_type(8))) short bf16x8;   // 8 bf16 (4 VGPRs)
typedef __attribute__((ext_vector_type(4))) float f32x4;    // MFMA accumulator
typedef unsigned int u32;

// global_load_lds, 16B per lane. LDS dest is wave-uniform base + lane*16 (m104);
// global src is per-lane (pre-swizzled there, rule 21).
#define GLOAD16(gp, lp) \
    __builtin_amdgcn_global_load_lds((const __attribute__((address_space(1))) u32*)(gp), \
                                     (__attribute__((address_space(3))) u32*)(lp), 16, 0, 0)

// ---- monotone float <-> uint key (for atomicMax on float incl. negatives) ----
__device__ __forceinline__ unsigned fenc(float x) {
    unsigned b = __float_as_uint(x);
    return (b & 0x80000000u) ? ~b : (b | 0x80000000u);
}
__device__ __forceinline__ float fdec(unsigned k) {
    unsigned b = (k & 0x80000000u) ? (k ^ 0x80000000u) : ~k;
    return __uint_as_float(b);
}

// ---- f32 pair -> packed bf16 hi / lo words ----
__device__ __forceinline__ void split2(float a, float b, u32* h, u32* l) {
    __hip_bfloat16 ha = __float2bfloat16(a);
    __hip_bfloat16 hb = __float2bfloat16(b);
    unsigned short ba, bb;
    __builtin_memcpy(&ba, &ha, 2); __builtin_memcpy(&bb, &hb, 2);
    float fa = __uint_as_float((u32)ba << 16);
    float fb = __uint_as_float((u32)bb << 16);
    __hip_bfloat16 la = __float2bfloat16(a - fa);
    __hip_bfloat16 lb = __float2bfloat16(b - fb);
    unsigned short ca, cb;
    __builtin_memcpy(&ca, &la, 2); __builtin_memcpy(&cb, &lb, 2);
    *h = (u32)ba | ((u32)bb << 16);
    *l = (u32)ca | ((u32)cb << 16);
}

// ============================================================================
// Kernel 0: split inputs into Hi/Lo bf16 arrays (row-major [BB][DD], packed).
// ============================================================================
__global__ __launch_bounds__(256) void split_kernel(const float* __restrict__ inp,
        u32* __restrict__ hi, u32* __restrict__ lo)
{
    const size_t e = ((size_t)blockIdx.x * 256 + threadIdx.x) * 8;
    float4 x0 = *(const float4*)(inp + e);
    float4 x1 = *(const float4*)(inp + e + 4);
    u32 h[4], l[4];
    split2(x0.x, x0.y, &h[0], &l[0]);
    split2(x0.z, x0.w, &h[1], &l[1]);
    split2(x1.x, x1.y, &h[2], &l[2]);
    split2(x1.z, x1.w, &h[3], &l[3]);
    *(uint4*)(hi + e / 2) = make_uint4(h[0], h[1], h[2], h[3]);
    *(uint4*)(lo + e / 2) = make_uint4(l[0], l[1], l[2], l[3]);
}

// ============================================================================
// Kernel 1: pos[i][g-1] = f_i . inputs[5i+g] (exact f32); posmin[i] = min
// ============================================================================
__global__ __launch_bounds__(256) void pos_kernel(const float* __restrict__ inp,
        float* __restrict__ pos, float* __restrict__ posmin)
{
    const int wid  = threadIdx.x >> 6;
    const int lane = threadIdx.x & 63;
    const int i = blockIdx.x * 4 + wid;
    const float* f = inp + (size_t)(5 * i) * DD + lane * 8;
    float4 fa = *(const float4*)(f);
    float4 fb = *(const float4*)(f + 4);
    float pmin = INFINITY;
    #pragma unroll
    for (int g = 1; g < 5; ++g) {
        const float* x = inp + (size_t)(5 * i + g) * DD + lane * 8;
        float4 xa = *(const float4*)(x);
        float4 xb = *(const float4*)(x + 4);
        float s = fa.x*xa.x + fa.y*xa.y + fa.z*xa.z + fa.w*xa.w
                + fb.x*xb.x + fb.y*xb.y + fb.z*xb.z + fb.w*xb.w;
        #pragma unroll
        for (int m = 1; m < 64; m <<= 1) s += __shfl_xor(s, m, 64);
        if (lane == 0) pos[i * 4 + (g - 1)] = s;
        pmin = fminf(pmin, s);
    }
    if (lane == 0) posmin[i] = pmin;
}

// ============================================================================
// Per-row LSE/max/count fold + atomics for one accumulator row-register.
// ============================================================================
__device__ __forceinline__ void row_epilogue(int i, int c0, int wc, int l15,
        float s0, float s1, float s2, float s3,
        const float* __restrict__ posmin, unsigned* __restrict__ negkey,
        double* __restrict__ msum, unsigned* __restrict__ cntn)
{
    const float th = posmin[i] - EPc;     // strict >
    float vmax = -INFINITY;
    float lM   = -INFINITY;
    float lS   = 0.f;
    int   vcnt = 0;
    float sv[4] = {s0, s1, s2, s3};
    float args[4]; bool msk[4];
    #pragma unroll
    for (int fc = 0; fc < 4; ++fc) {
        const int c = c0 + wc + fc * 16 + l15;
        const float s = sv[fc];
        const bool nonown = ((c / 5) != i);
        msk[fc]  = nonown && (s > th);
        args[fc] = BETAc * (s - LMDAc);
        if (nonown)  vmax = fmaxf(vmax, s);
        if (msk[fc]) { vcnt += 1; lM = fmaxf(lM, args[fc]); }
    }
    #pragma unroll
    for (int fc = 0; fc < 4; ++fc)
        if (msk[fc]) lS += __expf(args[fc] - lM);
    #pragma unroll
    for (int m = 1; m < 16; m <<= 1) {
        vmax  = fmaxf(vmax, __shfl_xor(vmax, m, 64));
        vcnt += __shfl_xor(vcnt, m, 64);
        float oM = __shfl_xor(lM, m, 64);
        float oS = __shfl_xor(lS, m, 64);
        if (oS != 0.f) {
            if (lS == 0.f)      { lM = oM; lS = oS; }
            else if (lM >= oM)  { lS += oS * __expf(oM - lM); }
            else                { lS = oS + lS * __expf(lM - oM); lM = oM; }
        }
    }
    if (l15 == 0) {
        atomicMax(&negkey[i], fenc(vmax));
        atomicAdd(&cntn[i], (unsigned)vcnt);
        if (lS > 0.f) {
            double e = (double)lM - SHIFT;
            if (e > 690.0) e = 690.0;
            double Dv = exp(e) * (double)lS;
            if (!(Dv < 1e300)) Dv = 1e300;    // also catches nan
            atomicAdd(&msum[i], Dv);
        }
    }
}

// ============================================================================
// Kernel 2 (fast path): MFMA sim GEMM, pre-split bf16, 2-phase double-buffered
// pipeline: STAGE(next) issued BEFORE COMPUTE(cur); single vmcnt(0)+barrier per
// K-step AFTER compute, so HBM latency hides under the MFMA phase.
// 128x128 tile, BK=32, 4 waves (64x64 each, 4x4 frags of 16x16x32).
// LDS 2 x 32 KB; chunk swizzle c^((row>>1)&3) on write (global-src side,
// rule 21) and on the ds_read side. Verified conflict-free (r6: 0 conflicts).
// ============================================================================
__global__ __launch_bounds__(256) void sim_mfma4(const u32* __restrict__ hi,
        const u32* __restrict__ lo, const float* __restrict__ posmin,
        unsigned* __restrict__ negkey, double* __restrict__ msum,
        unsigned* __restrict__ cntn)
{
    __shared__ u32 AsHi0[128*16], AsLo0[128*16], BsHi0[128*16], BsLo0[128*16];
    __shared__ u32 AsHi1[128*16], AsLo1[128*16], BsHi1[128*16], BsLo1[128*16];

    const int t    = threadIdx.x;
    const int bj   = blockIdx.x % (BB / 128);
    const int bi   = blockIdx.x / (BB / 128);
    const int i0   = bi * 128;
    const int c0   = bj * 128;
    const int lane = t & 63;
    const int w    = t >> 6;
    const int wr   = (w >> 1) * 64;
    const int wc   = (w & 1) * 64;
    const int l15  = lane & 15;
    const int l4   = lane >> 4;

    // ---- staging: wave w covers rows [w*32, w*32+32) of each array ----
    const int srow = w * 32 + (lane >> 2);      // +16 for the second GLOAD
    const int scp  = lane & 3;                  // stored chunk slot
    const int sc   = scp ^ ((srow >> 1) & 3);   // logical chunk fetched
    const size_t offA0 = (size_t)(5 * (i0 + srow))      * (DD * 2) + sc * 16;
    const size_t offA1 = (size_t)(5 * (i0 + srow + 16)) * (DD * 2) + sc * 16;
    const size_t offB0 = (size_t)(c0 + srow)      * (DD * 2) + sc * 16;
    const size_t offB1 = (size_t)(c0 + srow + 16) * (DD * 2) + sc * 16;
    const char* gAh0 = (const char*)hi + offA0;
    const char* gAh1 = (const char*)hi + offA1;
    const char* gAl0 = (const char*)lo + offA0;
    const char* gAl1 = (const char*)lo + offA1;
    const char* gBh0 = (const char*)hi + offB0;
    const char* gBh1 = (const char*)hi + offB1;
    const char* gBl0 = (const char*)lo + offB0;
    const char* gBl1 = (const char*)lo + offB1;
    const int dL0 = (w * 32) * 16;              // u32 index, wave-uniform
    const int dL1 = (w * 32 + 16) * 16;

#define STAGE(AH, AL, BH, BL, ks) do {                                   \
    const size_t kb_ = (size_t)(ks) * 64;                                \
    GLOAD16(gAh0 + kb_, (AH) + dL0); GLOAD16(gAh1 + kb_, (AH) + dL1);    \
    GLOAD16(gAl0 + kb_, (AL) + dL0); GLOAD16(gAl1 + kb_, (AL) + dL1);    \
    GLOAD16(gBh0 + kb_, (BH) + dL0); GLOAD16(gBh1 + kb_, (BH) + dL1);    \
    GLOAD16(gBl0 + kb_, (BL) + dL0); GLOAD16(gBl1 + kb_, (BL) + dL1);    \
} while (0)

    f32x4 acc[4][4];
    #pragma unroll
    for (int a = 0; a < 4; ++a)
        #pragma unroll
        for (int b = 0; b < 4; ++b) acc[a][b] = (f32x4)0.f;

    // swizzled LDS byte offsets for fragment reads
    int aoff[4], boff[4];
    #pragma unroll
    for (int f = 0; f < 4; ++f) {
        const int row = wr + f * 16 + l15;
        const int col = wc + f * 16 + l15;
        aoff[f] = row * 64 + ((l4 ^ ((row >> 1) & 3)) * 16);
        boff[f] = col * 64 + ((l4 ^ ((col >> 1) & 3)) * 16);
    }

#define COMPUTE(AH, AL, BH, BL) do {                                     \
    bf16x8 bh[4], bl[4];                                                 \
    _Pragma("unroll")                                                    \
    for (int fc = 0; fc < 4; ++fc) {                                     \
        bh[fc] = *(const bf16x8*)((const char*)(BH) + boff[fc]);         \
        bl[fc] = *(const bf16x8*)((const char*)(BL) + boff[fc]);         \
    }                                                                    \
    _Pragma("unroll")                                                    \
    for (int fr = 0; fr < 4; ++fr) {                                     \
        bf16x8 ah = *(const bf16x8*)((const char*)(AH) + aoff[fr]);      \
        bf16x8 al = *(const bf16x8*)((const char*)(AL) + aoff[fr]);      \
        _Pragma("unroll")                                                \
        for (int fc = 0; fc < 4; ++fc) {                                 \
            acc[fr][fc] = __builtin_amdgcn_mfma_f32_16x16x32_bf16(ah, bh[fc], acc[fr][fc], 0, 0, 0); \
            acc[fr][fc] = __builtin_amdgcn_mfma_f32_16x16x32_bf16(ah, bl[fc], acc[fr][fc], 0, 0, 0); \
            acc[fr][fc] = __builtin_amdgcn_mfma_f32_16x16x32_bf16(al, bh[fc], acc[fr][fc], 0, 0, 0); \
        }                                                                \
    }                                                                    \
} while (0)

    // prologue: fill buf0 for k-step 0
    STAGE(AsHi0, AsLo0, BsHi0, BsLo0, 0);
    asm volatile("s_waitcnt vmcnt(0)" ::: "memory");
    __syncthreads();

    // 16 K-steps, 2 per iteration (static buffer names; no runtime indexing)
    for (int it = 0; it < 8; ++it) {
        // phase A: compute k=2it from buf0, prefetch k=2it+1 into buf1
        STAGE(AsHi1, AsLo1, BsHi1, BsLo1, 2 * it + 1);
        COMPUTE(AsHi0, AsLo0, BsHi0, BsLo0);
        asm volatile("s_waitcnt vmcnt(0)" ::: "memory");
        __syncthreads();
        // phase B: compute k=2it+1 from buf1, prefetch k=2it+2 into buf0
        if (it < 7) STAGE(AsHi0, AsLo0, BsHi0, BsLo0, 2 * it + 2);
        COMPUTE(AsHi1, AsLo1, BsHi1, BsLo1);
        asm volatile("s_waitcnt vmcnt(0)" ::: "memory");
        __syncthreads();
    }
#undef STAGE
#undef COMPUTE

    // ---- fused epilogue. C/D layout: col = lane&15, row = (lane>>4)*4 + reg
    #pragma unroll
    for (int fr = 0; fr < 4; ++fr) {
        #pragma unroll
        for (int reg = 0; reg < 4; ++reg) {
            const int i = i0 + wr + fr * 16 + l4 * 4 + reg;
            row_epilogue(i, c0, wc, l15,
                         acc[fr][0][reg], acc[fr][1][reg],
                         acc[fr][2][reg], acc[fr][3][reg],
                         posmin, negkey, msum, cntn);
        }
    }
}

// ============================================================================
// Kernel 2 (fallback, ws too small): in-kernel cvt, known-good from round 4.
// ============================================================================
__device__ __forceinline__ void cvt8(const float* __restrict__ src,
                                     uint4* __restrict__ dhi, uint4* __restrict__ dlo)
{
    float4 x0 = *(const float4*)(src);
    float4 x1 = *(const float4*)(src + 4);
    float xs[8] = {x0.x, x0.y, x0.z, x0.w, x1.x, x1.y, x1.z, x1.w};
    u32 h[4], l[4];
    #pragma unroll
    for (int p = 0; p < 4; ++p) split2(xs[2*p], xs[2*p+1], &h[p], &l[p]);
    *dhi = make_uint4(h[0], h[1], h[2], h[3]);
    *dlo = make_uint4(l[0], l[1], l[2], l[3]);
}

__global__ __launch_bounds__(256) void sim_mfma(const float* __restrict__ inp,
        const float* __restrict__ posmin, unsigned* __restrict__ negkey,
        double* __restrict__ msum, unsigned* __restrict__ cntn)
{
    __shared__ uint4 AsHi[128][4];
    __shared__ uint4 AsLo[128][4];
    __shared__ uint4 BsHi[128][4];
    __shared__ uint4 BsLo[128][4];

    const int t    = threadIdx.x;
    const int bj   = blockIdx.x % (BB / 128);
    const int bi   = blockIdx.x / (BB / 128);
    const int i0   = bi * 128;
    const int c0   = bj * 128;
    const int lane = t & 63;
    const int w    = t >> 6;
    const int wr   = (w >> 1) * 64;
    const int wc   = (w & 1) * 64;
    const int l15  = lane & 15;
    const int l4   = lane >> 4;

    f32x4 acc[4][4];
    #pragma unroll
    for (int a = 0; a < 4; ++a)
        #pragma unroll
        for (int b = 0; b < 4; ++b) acc[a][b] = (f32x4)0.f;

    const int r0  = t >> 2;
    const int ch0 = t & 3;

    for (int kb = 0; kb < DD; kb += 32) {
        __syncthreads();
        #pragma unroll
        for (int half = 0; half < 2; ++half) {
            const int row = r0 + half * 64;
            const int cs  = ch0 ^ ((row >> 2) & 3);
            cvt8(inp + (size_t)(5 * (i0 + row)) * DD + kb + ch0 * 8,
                 &AsHi[row][cs], &AsLo[row][cs]);
            cvt8(inp + (size_t)(c0 + row) * DD + kb + ch0 * 8,
                 &BsHi[row][cs], &BsLo[row][cs]);
        }
        __syncthreads();

        bf16x8 bh[4], bl[4];
        #pragma unroll
        for (int fc = 0; fc < 4; ++fc) {
            const int col = wc + fc * 16 + l15;
            const int cs  = l4 ^ ((col >> 2) & 3);
            bh[fc] = *(const bf16x8*)&BsHi[col][cs];
            bl[fc] = *(const bf16x8*)&BsLo[col][cs];
        }
        #pragma unroll
        for (int fr = 0; fr < 4; ++fr) {
            const int row = wr + fr * 16 + l15;
            const int cs  = l4 ^ ((row >> 2) & 3);
            bf16x8 ah = *(const bf16x8*)&AsHi[row][cs];
            bf16x8 al = *(const bf16x8*)&AsLo[row][cs];
            #pragma unroll
            for (int fc = 0; fc < 4; ++fc) {
                acc[fr][fc] = __builtin_amdgcn_mfma_f32_16x16x32_bf16(ah, bh[fc], acc[fr][fc], 0, 0, 0);
                acc[fr][fc] = __builtin_amdgcn_mfma_f32_16x16x32_bf16(ah, bl[fc], acc[fr][fc], 0, 0, 0);
                acc[fr][fc] = __builtin_amdgcn_mfma_f32_16x16x32_bf16(al, bh[fc], acc[fr][fc], 0, 0, 0);
            }
        }
    }

    #pragma unroll
    for (int fr = 0; fr < 4; ++fr) {
        #pragma unroll
        for (int reg = 0; reg < 4; ++reg) {
            const int i = i0 + wr + fr * 16 + l4 * 4 + reg;
            row_epilogue(i, c0, wc, l15,
                         acc[fr][0][reg], acc[fr][1][reg],
                         acc[fr][2][reg], acc[fr][3][reg],
                         posmin, negkey, msum, cntn);
        }
    }
}

// ============================================================================
// Kernel 3: finalize.
// ============================================================================
__global__ __launch_bounds__(1024) void fin_kernel(const float* __restrict__ pos,
        const unsigned* __restrict__ negkey, const double* __restrict__ msum,
        const unsigned* __restrict__ cntn, float* __restrict__ out)
{
    const int t = threadIdx.x;
    double lossAcc = 0.0;
    int pAcc = 0, nAcc = 0;
    for (int r = t; r < NB; r += 1024) {
        const float negmax = fdec(negkey[r]);
        const float thr = negmax + EPc;       // strict <
        float Mp = -INFINITY; int pc = 0;
        float pa[4]; bool pm[4];
        #pragma unroll
        for (int g = 0; g < 4; ++g) {
            const float p = pos[r * 4 + g];
            pa[g] = -ALPHAc * (p - LMDAc);
            pm[g] = (p < thr);
            if (pm[g]) { pc += 1; Mp = fmaxf(Mp, pa[g]); }
        }
        double lp = 0.0;
        if (pc > 0) {
            float sp = 0.f;
            #pragma unroll
            for (int g = 0; g < 4; ++g)
                if (pm[g]) sp += __expf(pa[g] - Mp);
            double a = (double)Mp + log((double)sp);
            lp = (a > 30.0 ? a : log1p(exp(a))) / (double)ALPHAc;
        }
        double ln = 0.0;
        double Dsum = msum[r];
        if (Dsum > 0.0) {
            double a = SHIFT + log(Dsum);
            ln = (a > 30.0 ? a : log1p(exp(a))) / (double)BETAc;
        }
        double contrib = lp + ln;
        if (!(contrib < 1e30)) contrib = 1e30;
        lossAcc += contrib;
        pAcc += pc;
        nAcc += (int)cntn[r];
    }
    __shared__ double sl[1024];
    __shared__ int    sp_[1024];
    __shared__ int    sn_[1024];
    sl[t] = lossAcc; sp_[t] = pAcc; sn_[t] = nAcc;
    __syncthreads();
    for (int s = 512; s > 0; s >>= 1) {
        if (t < s) { sl[t] += sl[t + s]; sp_[t] += sp_[t + s]; sn_[t] += sn_[t + s]; }
        __syncthreads();
    }
    if (t == 0) {
        double loss = sl[0] / 4096.0;
        if (!(loss < 1e30)) loss = 1e30;
        out[0] = (float)loss;
        out[1] = (float)sp_[0] / 16384.0f;
        out[2] = (float)sn_[0] / 83865600.0f;
    }
}

// ============================================================================
extern "C" void kernel_launch(void* const* d_in, const int* in_sizes, int n_in,
                              void* d_out, int out_size, void* d_ws, size_t ws_size,
                              hipStream_t stream)
{
    (void)in_sizes; (void)n_in; (void)out_size;
    const float* inp = (const float*)d_in[0];   // (20480, 512) f32; targets unused
    char* ws = (char*)d_ws;
    // ws layout (bytes):
    //   [0      , 65536 )  pos      : 4096*4 f32
    //   [65536  , 81920 )  posmin   : 4096 f32
    //   [81920  , 98304 )  negkey   : 4096 u32
    //   [98304  , 131072)  msum     : 4096 f64
    //   [131072 , 147456)  cntn     : 4096 u32
    //   [147456 , +21.0MB)  Hi bf16 [BB][DD]
    //   [ ...   , +21.0MB)  Lo bf16 [BB][DD]
    float*    pos    = (float*)   (ws);
    float*    posmin = (float*)   (ws + 65536);
    unsigned* negkey = (unsigned*)(ws + 81920);
    double*   msum   = (double*)  (ws + 98304);
    unsigned* cntn   = (unsigned*)(ws + 131072);
    u32*      hi     = (u32*)     (ws + 147456);
    u32*      lo     = (u32*)     (ws + 147456 + (size_t)BB * DD * 2);
    float*    out    = (float*)d_out;
    const size_t need = 147456 + (size_t)BB * DD * 4;   // 42.1 MB

    hipMemsetAsync(ws + 81920, 0, 65536, stream);
    hipLaunchKernelGGL(pos_kernel, dim3(NB / 4), dim3(256), 0, stream, inp, pos, posmin);

    if (ws_size >= need) {
        hipLaunchKernelGGL(split_kernel, dim3(BB * DD / (256 * 8)), dim3(256), 0, stream,
                           inp, hi, lo);
        hipLaunchKernelGGL(sim_mfma4, dim3((NB / 128) * (BB / 128)), dim3(256), 0, stream,
                           hi, lo, posmin, negkey, msum, cntn);
    } else {
        hipLaunchKernelGGL(sim_mfma, dim3((NB / 128) * (BB / 128)), dim3(256), 0, stream,
                           inp, posmin, negkey, msum, cntn);
    }
    hipLaunchKernelGGL(fin_kernel, dim3(1), dim3(1024), 0, stream, pos, negkey, msum, cntn, out);
}

// Round 9
// 513.575 us; speedup vs baseline: 1.4903x; 1.0235x over previous
//
#include <hip/hip_runtime.h>
#include <hip/hip_bf16.h>
#include <math.h>

// Problem constants (fixed by the reference)
#define NB    4096      // number of anchors  (B / GROUP)
#define BB    20480     // total rows of inputs = columns of sim
#define DD    512       // feature dim
#define EPc    0.1f
#define BETAc  10.0f
#define ALPHAc 2.0f
#define LMDAc  1.0f
// LSE shift: masked args BETA*(s-1) span ~[-700, 1400].
#define SHIFT  1400.0

typedef __attribute__((ext_vector_type(8))) short bf16x8;   // 8 bf16 (4 VGPRs)
typedef __attribute__((ext_vector_type(4))) float f32x4;    // MFMA accumulator
typedef unsigned int u32;

// global_load_lds, 16B per lane. LDS dest is wave-uniform base + lane*16 (m104);
// global src is per-lane (pre-swizzled there, rule 21).
#define GLOAD16(gp, lp) \
    __builtin_amdgcn_global_load_lds((const __attribute__((address_space(1))) u32*)(gp), \
                                     (__attribute__((address_space(3))) u32*)(lp), 16, 0, 0)

// ---- monotone float <-> uint key (for atomicMax on float incl. negatives) ----
__device__ __forceinline__ unsigned fenc(float x) {
    unsigned b = __float_as_uint(x);
    return (b & 0x80000000u) ? ~b : (b | 0x80000000u);
}
__device__ __forceinline__ float fdec(unsigned k) {
    unsigned b = (k & 0x80000000u) ? (k ^ 0x80000000u) : ~k;
    return __uint_as_float(b);
}

// ---- f32 pair -> packed bf16 hi / lo words ----
__device__ __forceinline__ void split2(float a, float b, u32* h, u32* l) {
    __hip_bfloat16 ha = __float2bfloat16(a);
    __hip_bfloat16 hb = __float2bfloat16(b);
    unsigned short ba, bb;
    __builtin_memcpy(&ba, &ha, 2); __builtin_memcpy(&bb, &hb, 2);
    float fa = __uint_as_float((u32)ba << 16);
    float fb = __uint_as_float((u32)bb << 16);
    __hip_bfloat16 la = __float2bfloat16(a - fa);
    __hip_bfloat16 lb = __float2bfloat16(b - fb);
    unsigned short ca, cb;
    __builtin_memcpy(&ca, &la, 2); __builtin_memcpy(&cb, &lb, 2);
    *h = (u32)ba | ((u32)bb << 16);
    *l = (u32)ca | ((u32)cb << 16);
}

// ============================================================================
// Kernel 0: split inputs into Hi/Lo bf16 arrays (row-major [BB][DD], packed).
// ============================================================================
__global__ __launch_bounds__(256) void split_kernel(const float* __restrict__ inp,
        u32* __restrict__ hi, u32* __restrict__ lo)
{
    const size_t e = ((size_t)blockIdx.x * 256 + threadIdx.x) * 8;
    float4 x0 = *(const float4*)(inp + e);
    float4 x1 = *(const float4*)(inp + e + 4);
    u32 h[4], l[4];
    split2(x0.x, x0.y, &h[0], &l[0]);
    split2(x0.z, x0.w, &h[1], &l[1]);
    split2(x1.x, x1.y, &h[2], &l[2]);
    split2(x1.z, x1.w, &h[3], &l[3]);
    *(uint4*)(hi + e / 2) = make_uint4(h[0], h[1], h[2], h[3]);
    *(uint4*)(lo + e / 2) = make_uint4(l[0], l[1], l[2], l[3]);
}

// ============================================================================
// Kernel 1: pos[i][g-1] = f_i . inputs[5i+g] (exact f32); posmin[i] = min
// ============================================================================
__global__ __launch_bounds__(256) void pos_kernel(const float* __restrict__ inp,
        float* __restrict__ pos, float* __restrict__ posmin)
{
    const int wid  = threadIdx.x >> 6;
    const int lane = threadIdx.x & 63;
    const int i = blockIdx.x * 4 + wid;
    const float* f = inp + (size_t)(5 * i) * DD + lane * 8;
    float4 fa = *(const float4*)(f);
    float4 fb = *(const float4*)(f + 4);
    float pmin = INFINITY;
    #pragma unroll
    for (int g = 1; g < 5; ++g) {
        const float* x = inp + (size_t)(5 * i + g) * DD + lane * 8;
        float4 xa = *(const float4*)(x);
        float4 xb = *(const float4*)(x + 4);
        float s = fa.x*xa.x + fa.y*xa.y + fa.z*xa.z + fa.w*xa.w
                + fb.x*xb.x + fb.y*xb.y + fb.z*xb.z + fb.w*xb.w;
        #pragma unroll
        for (int m = 1; m < 64; m <<= 1) s += __shfl_xor(s, m, 64);
        if (lane == 0) pos[i * 4 + (g - 1)] = s;
        pmin = fminf(pmin, s);
    }
    if (lane == 0) posmin[i] = pmin;
}

// ============================================================================
// Per-row LSE/max/count fold + atomics for one accumulator row-register.
// ============================================================================
__device__ __forceinline__ void row_epilogue(int i, int c0, int wc, int l15,
        float s0, float s1, float s2, float s3,
        const float* __restrict__ posmin, unsigned* __restrict__ negkey,
        double* __restrict__ msum, unsigned* __restrict__ cntn)
{
    const float th = posmin[i] - EPc;     // strict >
    float vmax = -INFINITY;
    float lM   = -INFINITY;
    float lS   = 0.f;
    int   vcnt = 0;
    float sv[4] = {s0, s1, s2, s3};
    float args[4]; bool msk[4];
    #pragma unroll
    for (int fc = 0; fc < 4; ++fc) {
        const int c = c0 + wc + fc * 16 + l15;
        const float s = sv[fc];
        const bool nonown = ((c / 5) != i);
        msk[fc]  = nonown && (s > th);
        args[fc] = BETAc * (s - LMDAc);
        if (nonown)  vmax = fmaxf(vmax, s);
        if (msk[fc]) { vcnt += 1; lM = fmaxf(lM, args[fc]); }
    }
    #pragma unroll
    for (int fc = 0; fc < 4; ++fc)
        if (msk[fc]) lS += __expf(args[fc] - lM);
    #pragma unroll
    for (int m = 1; m < 16; m <<= 1) {
        vmax  = fmaxf(vmax, __shfl_xor(vmax, m, 64));
        vcnt += __shfl_xor(vcnt, m, 64);
        float oM = __shfl_xor(lM, m, 64);
        float oS = __shfl_xor(lS, m, 64);
        if (oS != 0.f) {
            if (lS == 0.f)      { lM = oM; lS = oS; }
            else if (lM >= oM)  { lS += oS * __expf(oM - lM); }
            else                { lS = oS + lS * __expf(lM - oM); lM = oM; }
        }
    }
    if (l15 == 0) {
        atomicMax(&negkey[i], fenc(vmax));
        atomicAdd(&cntn[i], (unsigned)vcnt);
        if (lS > 0.f) {
            double e = (double)lM - SHIFT;
            if (e > 690.0) e = 690.0;
            double Dv = exp(e) * (double)lS;
            if (!(Dv < 1e300)) Dv = 1e300;    // also catches nan
            atomicAdd(&msum[i], Dv);
        }
    }
}

// ============================================================================
// Kernel 2 (fast path): MFMA sim GEMM, pre-split bf16, counted-vmcnt pipeline
// (T4): raw s_barrier (NOT __syncthreads -> no implicit full drain) and
// s_waitcnt vmcnt(8) in the steady state (next buffer's 8 loads stay in
// flight across the barrier). Tail peeled with vmcnt(8)/vmcnt(0).
// 128x128 tile, BK=32, 4 waves (64x64 each, 4x4 frags of 16x16x32).
// LDS 2 x 32 KB; chunk swizzle c^((row>>1)&3) on write (global-src side,
// rule 21) and on the ds_read side. Verified conflict-free (r6/r8: 0).
// ============================================================================
__global__ __launch_bounds__(256) void sim_mfma5(const u32* __restrict__ hi,
        const u32* __restrict__ lo, const float* __restrict__ posmin,
        unsigned* __restrict__ negkey, double* __restrict__ msum,
        unsigned* __restrict__ cntn)
{
    __shared__ u32 AsHi0[128*16], AsLo0[128*16], BsHi0[128*16], BsLo0[128*16];
    __shared__ u32 AsHi1[128*16], AsLo1[128*16], BsHi1[128*16], BsLo1[128*16];

    const int t    = threadIdx.x;
    const int bj   = blockIdx.x % (BB / 128);
    const int bi   = blockIdx.x / (BB / 128);
    const int i0   = bi * 128;
    const int c0   = bj * 128;
    const int lane = t & 63;
    const int w    = t >> 6;
    const int wr   = (w >> 1) * 64;
    const int wc   = (w & 1) * 64;
    const int l15  = lane & 15;
    const int l4   = lane >> 4;

    // ---- staging: wave w covers rows [w*32, w*32+32) of each array ----
    const int srow = w * 32 + (lane >> 2);      // +16 for the second GLOAD
    const int scp  = lane & 3;                  // stored chunk slot
    const int sc   = scp ^ ((srow >> 1) & 3);   // logical chunk fetched
    const size_t offA0 = (size_t)(5 * (i0 + srow))      * (DD * 2) + sc * 16;
    const size_t offA1 = (size_t)(5 * (i0 + srow + 16)) * (DD * 2) + sc * 16;
    const size_t offB0 = (size_t)(c0 + srow)      * (DD * 2) + sc * 16;
    const size_t offB1 = (size_t)(c0 + srow + 16) * (DD * 2) + sc * 16;
    const char* gAh0 = (const char*)hi + offA0;
    const char* gAh1 = (const char*)hi + offA1;
    const char* gAl0 = (const char*)lo + offA0;
    const char* gAl1 = (const char*)lo + offA1;
    const char* gBh0 = (const char*)hi + offB0;
    const char* gBh1 = (const char*)hi + offB1;
    const char* gBl0 = (const char*)lo + offB0;
    const char* gBl1 = (const char*)lo + offB1;
    const int dL0 = (w * 32) * 16;              // u32 index, wave-uniform
    const int dL1 = (w * 32 + 16) * 16;

#define STAGE(AH, AL, BH, BL, ks) do {                                   \
    const size_t kb_ = (size_t)(ks) * 64;                                \
    GLOAD16(gAh0 + kb_, (AH) + dL0); GLOAD16(gAh1 + kb_, (AH) + dL1);    \
    GLOAD16(gAl0 + kb_, (AL) + dL0); GLOAD16(gAl1 + kb_, (AL) + dL1);    \
    GLOAD16(gBh0 + kb_, (BH) + dL0); GLOAD16(gBh1 + kb_, (BH) + dL1);    \
    GLOAD16(gBl0 + kb_, (BL) + dL0); GLOAD16(gBl1 + kb_, (BL) + dL1);    \
} while (0)

    f32x4 acc[4][4];
    #pragma unroll
    for (int a = 0; a < 4; ++a)
        #pragma unroll
        for (int b = 0; b < 4; ++b) acc[a][b] = (f32x4)0.f;

    // swizzled LDS byte offsets for fragment reads
    int aoff[4], boff[4];
    #pragma unroll
    for (int f = 0; f < 4; ++f) {
        const int row = wr + f * 16 + l15;
        const int col = wc + f * 16 + l15;
        aoff[f] = row * 64 + ((l4 ^ ((row >> 1) & 3)) * 16);
        boff[f] = col * 64 + ((l4 ^ ((col >> 1) & 3)) * 16);
    }

#define COMPUTE(AH, AL, BH, BL) do {                                     \
    bf16x8 bh[4], bl[4];                                                 \
    _Pragma("unroll")                                                    \
    for (int fc = 0; fc < 4; ++fc) {                                     \
        bh[fc] = *(const bf16x8*)((const char*)(BH) + boff[fc]);         \
        bl[fc] = *(const bf16x8*)((const char*)(BL) + boff[fc]);         \
    }                                                                    \
    _Pragma("unroll")                                                    \
    for (int fr = 0; fr < 4; ++fr) {                                     \
        bf16x8 ah = *(const bf16x8*)((const char*)(AH) + aoff[fr]);      \
        bf16x8 al = *(const bf16x8*)((const char*)(AL) + aoff[fr]);      \
        _Pragma("unroll")                                                \
        for (int fc = 0; fc < 4; ++fc) {                                 \
            acc[fr][fc] = __builtin_amdgcn_mfma_f32_16x16x32_bf16(ah, bh[fc], acc[fr][fc], 0, 0, 0); \
            acc[fr][fc] = __builtin_amdgcn_mfma_f32_16x16x32_bf16(ah, bl[fc], acc[fr][fc], 0, 0, 0); \
            acc[fr][fc] = __builtin_amdgcn_mfma_f32_16x16x32_bf16(al, bh[fc], acc[fr][fc], 0, 0, 0); \
        }                                                                \
    }                                                                    \
} while (0)

#define VMCNT8  asm volatile("s_waitcnt vmcnt(8)" ::: "memory")
#define VMCNT0  asm volatile("s_waitcnt vmcnt(0)" ::: "memory")
#define MFENCE  asm volatile("" ::: "memory")
#define BARRIER __builtin_amdgcn_s_barrier()

    // prologue: both buffers in flight (16 outstanding loads)
    STAGE(AsHi0, AsLo0, BsHi0, BsLo0, 0);
    STAGE(AsHi1, AsLo1, BsHi1, BsLo1, 1);

    // steady state: k = 0..13 (7 iterations x 2 phases); vmcnt(8) waits the
    // OLDEST 8 loads (current buffer) while the next buffer's 8 keep flying.
    for (int it = 0; it < 7; ++it) {
        VMCNT8; BARRIER; MFENCE;
        COMPUTE(AsHi0, AsLo0, BsHi0, BsLo0);
        BARRIER; MFENCE;                      // all waves done reading buf0
        STAGE(AsHi0, AsLo0, BsHi0, BsLo0, 2 * it + 2);
        VMCNT8; BARRIER; MFENCE;
        COMPUTE(AsHi1, AsLo1, BsHi1, BsLo1);
        BARRIER; MFENCE;                      // all waves done reading buf1
        STAGE(AsHi1, AsLo1, BsHi1, BsLo1, 2 * it + 3);
    }
    // tail: k=14 (buf0; 8 younger loads [k=15] still outstanding -> vmcnt(8))
    VMCNT8; BARRIER; MFENCE;
    COMPUTE(AsHi0, AsLo0, BsHi0, BsLo0);
    // tail: k=15 (buf1; nothing younger -> vmcnt(0))
    VMCNT0; BARRIER; MFENCE;
    COMPUTE(AsHi1, AsLo1, BsHi1, BsLo1);

#undef STAGE
#undef COMPUTE
#undef VMCNT8
#undef VMCNT0
#undef MFENCE
#undef BARRIER

    // ---- fused epilogue. C/D layout: col = lane&15, row = (lane>>4)*4 + reg
    #pragma unroll
    for (int fr = 0; fr < 4; ++fr) {
        #pragma unroll
        for (int reg = 0; reg < 4; ++reg) {
            const int i = i0 + wr + fr * 16 + l4 * 4 + reg;
            row_epilogue(i, c0, wc, l15,
                         acc[fr][0][reg], acc[fr][1][reg],
                         acc[fr][2][reg], acc[fr][3][reg],
                         posmin, negkey, msum, cntn);
        }
    }
}

// ============================================================================
// Kernel 2 (fallback, ws too small): in-kernel cvt, known-good from round 4.
// ============================================================================
__device__ __forceinline__ void cvt8(const float* __restrict__ src,
                                     uint4* __restrict__ dhi, uint4* __restrict__ dlo)
{
    float4 x0 = *(const float4*)(src);
    float4 x1 = *(const float4*)(src + 4);
    float xs[8] = {x0.x, x0.y, x0.z, x0.w, x1.x, x1.y, x1.z, x1.w};
    u32 h[4], l[4];
    #pragma unroll
    for (int p = 0; p < 4; ++p) split2(xs[2*p], xs[2*p+1], &h[p], &l[p]);
    *dhi = make_uint4(h[0], h[1], h[2], h[3]);
    *dlo = make_uint4(l[0], l[1], l[2], l[3]);
}

__global__ __launch_bounds__(256) void sim_mfma(const float* __restrict__ inp,
        const float* __restrict__ posmin, unsigned* __restrict__ negkey,
        double* __restrict__ msum, unsigned* __restrict__ cntn)
{
    __shared__ uint4 AsHi[128][4];
    __shared__ uint4 AsLo[128][4];
    __shared__ uint4 BsHi[128][4];
    __shared__ uint4 BsLo[128][4];

    const int t    = threadIdx.x;
    const int bj   = blockIdx.x % (BB / 128);
    const int bi   = blockIdx.x / (BB / 128);
    const int i0   = bi * 128;
    const int c0   = bj * 128;
    const int lane = t & 63;
    const int w    = t >> 6;
    const int wr   = (w >> 1) * 64;
    const int wc   = (w & 1) * 64;
    const int l15  = lane & 15;
    const int l4   = lane >> 4;

    f32x4 acc[4][4];
    #pragma unroll
    for (int a = 0; a < 4; ++a)
        #pragma unroll
        for (int b = 0; b < 4; ++b) acc[a][b] = (f32x4)0.f;

    const int r0  = t >> 2;
    const int ch0 = t & 3;

    for (int kb = 0; kb < DD; kb += 32) {
        __syncthreads();
        #pragma unroll
        for (int half = 0; half < 2; ++half) {
            const int row = r0 + half * 64;
            const int cs  = ch0 ^ ((row >> 2) & 3);
            cvt8(inp + (size_t)(5 * (i0 + row)) * DD + kb + ch0 * 8,
                 &AsHi[row][cs], &AsLo[row][cs]);
            cvt8(inp + (size_t)(c0 + row) * DD + kb + ch0 * 8,
                 &BsHi[row][cs], &BsLo[row][cs]);
        }
        __syncthreads();

        bf16x8 bh[4], bl[4];
        #pragma unroll
        for (int fc = 0; fc < 4; ++fc) {
            const int col = wc + fc * 16 + l15;
            const int cs  = l4 ^ ((col >> 2) & 3);
            bh[fc] = *(const bf16x8*)&BsHi[col][cs];
            bl[fc] = *(const bf16x8*)&BsLo[col][cs];
        }
        #pragma unroll
        for (int fr = 0; fr < 4; ++fr) {
            const int row = wr + fr * 16 + l15;
            const int cs  = l4 ^ ((row >> 2) & 3);
            bf16x8 ah = *(const bf16x8*)&AsHi[row][cs];
            bf16x8 al = *(const bf16x8*)&AsLo[row][cs];
            #pragma unroll
            for (int fc = 0; fc < 4; ++fc) {
                acc[fr][fc] = __builtin_amdgcn_mfma_f32_16x16x32_bf16(ah, bh[fc], acc[fr][fc], 0, 0, 0);
                acc[fr][fc] = __builtin_amdgcn_mfma_f32_16x16x32_bf16(ah, bl[fc], acc[fr][fc], 0, 0, 0);
                acc[fr][fc] = __builtin_amdgcn_mfma_f32_16x16x32_bf16(al, bh[fc], acc[fr][fc], 0, 0, 0);
            }
        }
    }

    #pragma unroll
    for (int fr = 0; fr < 4; ++fr) {
        #pragma unroll
        for (int reg = 0; reg < 4; ++reg) {
            const int i = i0 + wr + fr * 16 + l4 * 4 + reg;
            row_epilogue(i, c0, wc, l15,
                         acc[fr][0][reg], acc[fr][1][reg],
                         acc[fr][2][reg], acc[fr][3][reg],
                         posmin, negkey, msum, cntn);
        }
    }
}

// ============================================================================
// Kernel 3: finalize.
// ============================================================================
__global__ __launch_bounds__(1024) void fin_kernel(const float* __restrict__ pos,
        const unsigned* __restrict__ negkey, const double* __restrict__ msum,
        const unsigned* __restrict__ cntn, float* __restrict__ out)
{
    const int t = threadIdx.x;
    double lossAcc = 0.0;
    int pAcc = 0, nAcc = 0;
    for (int r = t; r < NB; r += 1024) {
        const float negmax = fdec(negkey[r]);
        const float thr = negmax + EPc;       // strict <
        float Mp = -INFINITY; int pc = 0;
        float pa[4]; bool pm[4];
        #pragma unroll
        for (int g = 0; g < 4; ++g) {
            const float p = pos[r * 4 + g];
            pa[g] = -ALPHAc * (p - LMDAc);
            pm[g] = (p < thr);
            if (pm[g]) { pc += 1; Mp = fmaxf(Mp, pa[g]); }
        }
        double lp = 0.0;
        if (pc > 0) {
            float sp = 0.f;
            #pragma unroll
            for (int g = 0; g < 4; ++g)
                if (pm[g]) sp += __expf(pa[g] - Mp);
            double a = (double)Mp + log((double)sp);
            lp = (a > 30.0 ? a : log1p(exp(a))) / (double)ALPHAc;
        }
        double ln = 0.0;
        double Dsum = msum[r];
        if (Dsum > 0.0) {
            double a = SHIFT + log(Dsum);
            ln = (a > 30.0 ? a : log1p(exp(a))) / (double)BETAc;
        }
        double contrib = lp + ln;
        if (!(contrib < 1e30)) contrib = 1e30;
        lossAcc += contrib;
        pAcc += pc;
        nAcc += (int)cntn[r];
    }
    __shared__ double sl[1024];
    __shared__ int    sp_[1024];
    __shared__ int    sn_[1024];
    sl[t] = lossAcc; sp_[t] = pAcc; sn_[t] = nAcc;
    __syncthreads();
    for (int s = 512; s > 0; s >>= 1) {
        if (t < s) { sl[t] += sl[t + s]; sp_[t] += sp_[t + s]; sn_[t] += sn_[t + s]; }
        __syncthreads();
    }
    if (t == 0) {
        double loss = sl[0] / 4096.0;
        if (!(loss < 1e30)) loss = 1e30;
        out[0] = (float)loss;
        out[1] = (float)sp_[0] / 16384.0f;
        out[2] = (float)sn_[0] / 83865600.0f;
    }
}

// ============================================================================
extern "C" void kernel_launch(void* const* d_in, const int* in_sizes, int n_in,
                              void* d_out, int out_size, void* d_ws, size_t ws_size,
                              hipStream_t stream)
{
    (void)in_sizes; (void)n_in; (void)out_size;
    const float* inp = (const float*)d_in[0];   // (20480, 512) f32; targets unused
    char* ws = (char*)d_ws;
    // ws layout (bytes):
    //   [0      , 65536 )  pos      : 4096*4 f32
    //   [65536  , 81920 )  posmin   : 4096 f32
    //   [81920  , 98304 )  negkey   : 4096 u32
    //   [98304  , 131072)  msum     : 4096 f64
    //   [131072 , 147456)  cntn     : 4096 u32
    //   [147456 , +21.0MB)  Hi bf16 [BB][DD]
    //   [ ...   , +21.0MB)  Lo bf16 [BB][DD]
    float*    pos    = (float*)   (ws);
    float*    posmin = (float*)   (ws + 65536);
    unsigned* negkey = (unsigned*)(ws + 81920);
    double*   msum   = (double*)  (ws + 98304);
    unsigned* cntn   = (unsigned*)(ws + 131072);
    u32*      hi     = (u32*)     (ws + 147456);
    u32*      lo     = (u32*)     (ws + 147456 + (size_t)BB * DD * 2);
    float*    out    = (float*)d_out;
    const size_t need = 147456 + (size_t)BB * DD * 4;   // 42.1 MB

    hipMemsetAsync(ws + 81920, 0, 65536, stream);
    hipLaunchKernelGGL(pos_kernel, dim3(NB / 4), dim3(256), 0, stream, inp, pos, posmin);

    if (ws_size >= need) {
        hipLaunchKernelGGL(split_kernel, dim3(BB * DD / (256 * 8)), dim3(256), 0, stream,
                           inp, hi, lo);
        hipLaunchKernelGGL(sim_mfma5, dim3((NB / 128) * (BB / 128)), dim3(256), 0, stream,
                           hi, lo, posmin, negkey, msum, cntn);
    } else {
        hipLaunchKernelGGL(sim_mfma, dim3((NB / 128) * (BB / 128)), dim3(256), 0, stream,
                           inp, posmin, negkey, msum, cntn);
    }
    hipLaunchKernelGGL(fin_kernel, dim3(1), dim3(1024), 0, stream, pos, negkey, msum, cntn, out);
}